// Round 1
// baseline (1935.876 us; speedup 1.0000x reference)
//
#include <hip/hip_runtime.h>
#include <hip/hip_bf16.h>

typedef __bf16 bf16_t;
typedef __bf16 bf16x8 __attribute__((ext_vector_type(8)));
typedef float  f32x4  __attribute__((ext_vector_type(4)));

// ---------------- workspace layout (bytes) ----------------
#define WBT_OFF   0                                  // bf16 [12][96][384]  (qkv weights, transposed per head: [col][k])
#define PWB_OFF   (12*96*384*2)                      // bf16 [384][384]     (proj_w, row-major, same as source)
#define BIASL_OFF (PWB_OFF + 384*384*2)              // f32  [12][4][4][64][4]  (bias pre-gathered in C-frag layout)
#define QKVB_OFF  (BIASL_OFF + 12*4*4*64*4*4)        // f32  [12][96]       (qkv bias remapped)
// total ws needed = QKVB_OFF + 12*96*4 = 1,380,864 B

// ---------------- LDS layout (bytes) ----------------
#define LDS_XS   0        // bf16 [64][384], row stride 768 B, XOR-swizzled
#define LDS_BSW  49152    // bf16 [96][384], row stride 768 B, XOR-swizzled
#define LDS_QS   122880   // bf16 [64][36],  row stride 72 B
#define LDS_KS   127488   // bf16 [64][36],  row stride 72 B
#define LDS_VST  132096   // bf16 [32][72],  row stride 144 B  (V transposed: [d][j])
#define LDS_P    136704   // bf16 [64][72],  row stride 144 B  (softmax probs)
#define LDS_OS   145920   // bf16 [64][36],  row stride 72 B   (per-head attn out)
#define LDS_TOT  150528

__global__ void prep_kernel(const float* __restrict__ qkv_w,
                            const float* __restrict__ qkv_b,
                            const float* __restrict__ proj_w,
                            const float* __restrict__ rpb,
                            const int*   __restrict__ rel_idx,
                            char* __restrict__ ws)
{
    bf16_t* WbT   = (bf16_t*)(ws + WBT_OFF);
    bf16_t* pwb   = (bf16_t*)(ws + PWB_OFF);
    float*  biasL = (float*)(ws + BIASL_OFF);
    float*  qkvbL = (float*)(ws + QKVB_OFF);
    const int n_wbt  = 12*96*384;
    const int n_pwb  = 384*384;
    const int n_bias = 12*4*4*64*4;
    const int n_qb   = 12*96;
    int idx = blockIdx.x * blockDim.x + threadIdx.x;
    if (idx < n_wbt) {
        int h = idx / (96*384);
        int rem = idx % (96*384);
        int c = rem / 384, k = rem % 384;
        int s = c >> 5, cc = c & 31;           // s: 0=q,1=k,2=v
        WbT[idx] = (bf16_t)qkv_w[(s*384 + h*32 + cc)*384 + k];
    } else if (idx < n_wbt + n_pwb) {
        int i = idx - n_wbt;
        pwb[i] = (bf16_t)proj_w[i];
    } else if (idx < n_wbt + n_pwb + n_bias) {
        int li = idx - n_wbt - n_pwb;          // [h][m][ct][l][r]
        int r  = li & 3;
        int l  = (li >> 2) & 63;
        int ct = (li >> 8) & 3;
        int m  = (li >> 10) & 3;
        int h  = li >> 12;
        int i  = m*16 + ((l >> 4) << 2) + r;   // token row
        int j  = ct*16 + (l & 15);             // token col
        float v = 0.f;
        if (i < 49 && j < 49) v = rpb[rel_idx[i*49 + j]*12 + h];
        biasL[li] = v;
    } else if (idx < n_wbt + n_pwb + n_bias + n_qb) {
        int i = idx - n_wbt - n_pwb - n_bias;
        int h = i / 96, c = i % 96;
        int s = c >> 5, cc = c & 31;
        qkvbL[i] = qkv_b[s*384 + h*32 + cc];
    }
}

__launch_bounds__(512, 2)
__global__ void wattn_kernel(const float* __restrict__ x,
                             const float* __restrict__ proj_b,
                             const char*  __restrict__ ws,
                             float* __restrict__ out)
{
    __shared__ __attribute__((aligned(16))) char smem[LDS_TOT];

    const bf16_t* WbT   = (const bf16_t*)(ws + WBT_OFF);
    const bf16_t* pwb   = (const bf16_t*)(ws + PWB_OFF);
    const float4* biasL = (const float4*)(ws + BIASL_OFF);
    const float*  qkvbL = (const float*)(ws + QKVB_OFF);

    const int tid  = threadIdx.x;
    const int lane = tid & 63;
    const int w    = tid >> 6;      // wave 0..7
    const int lo   = lane & 15;
    const int hi   = lane >> 4;
    const int wi   = blockIdx.x;    // window index

    auto xs_addr = [&](int row, int kb) { return LDS_XS  + row*768 + (kb ^ ((row & 7) << 4)); };
    auto bs_addr = [&](int row, int kb) { return LDS_BSW + row*768 + (kb ^ ((row & 7) << 4)); };

    // ---- init: zero Xs pad rows (49..63) and all of P ----
    uint4 z4 = make_uint4(0u, 0u, 0u, 0u);
    for (int c = tid; c < 15*48; c += 512) {
        int row = 49 + c/48, kc = c%48;
        *(uint4*)(smem + xs_addr(row, kc*16)) = z4;
    }
    for (int c = tid; c < 9216/16; c += 512)
        *(uint4*)(smem + LDS_P + c*16) = z4;

    // ---- stage x (fp32 -> bf16, swizzled) ----
    const float* xw = x + (size_t)wi * (49*384);
    for (int c = tid; c < 49*48; c += 512) {
        int row = c/48, kc = c%48;
        float4 f0 = *(const float4*)(xw + row*384 + kc*8);
        float4 f1 = *(const float4*)(xw + row*384 + kc*8 + 4);
        bf16x8 t;
        t[0]=(bf16_t)f0.x; t[1]=(bf16_t)f0.y; t[2]=(bf16_t)f0.z; t[3]=(bf16_t)f0.w;
        t[4]=(bf16_t)f1.x; t[5]=(bf16_t)f1.y; t[6]=(bf16_t)f1.z; t[7]=(bf16_t)f1.w;
        *(bf16x8*)(smem + xs_addr(row, kc*16)) = t;
    }
    __syncthreads();

    const float scale = 0.17677669529663687f; // 1/sqrt(32)
    f32x4 accP[12];
#pragma unroll
    for (int i = 0; i < 12; ++i) accP[i] = f32x4{0.f, 0.f, 0.f, 0.f};

    const int mq = w >> 1;  // PV/proj m-tile
    const int nq = w & 1;   // PV n-tile / proj col-half

#pragma unroll 1
    for (int h = 0; h < 12; ++h) {
        // ---- stage per-head qkv weight slice [96][384] bf16 into LDS ----
        const bf16_t* wsrc = WbT + h*(96*384);
        for (int c = tid; c < 96*48; c += 512) {
            int row = c/48, kc = c%48;
            uint4 d = *(const uint4*)(wsrc + row*384 + kc*8);
            *(uint4*)(smem + bs_addr(row, kc*16)) = d;
        }
        __syncthreads();

        // ---- QKV GEMM: wave (m = w&3, nh2 = w>>2) computes cols nh2*48 + ct*16 ----
        {
            const int m = w & 3, nh2 = w >> 2;
            f32x4 acc[3];
#pragma unroll
            for (int i = 0; i < 3; ++i) acc[i] = f32x4{0.f,0.f,0.f,0.f};
#pragma unroll
            for (int kk = 0; kk < 12; ++kk) {
                bf16x8 a = *(const bf16x8*)(smem + xs_addr(m*16 + lo, kk*64 + hi*16));
#pragma unroll
                for (int ct = 0; ct < 3; ++ct) {
                    bf16x8 b = *(const bf16x8*)(smem + bs_addr(nh2*48 + ct*16 + lo, kk*64 + hi*16));
                    acc[ct] = __builtin_amdgcn_mfma_f32_16x16x32_bf16(a, b, acc[ct], 0, 0, 0);
                }
            }
            // bias add + scatter to Qs/Ks/VsT
#pragma unroll
            for (int ct = 0; ct < 3; ++ct) {
                int tct = nh2*3 + ct;                 // 0..5: 0,1=q  2,3=k  4,5=v
                float qb = qkvbL[h*96 + tct*16 + lo];
                int row0 = (w & 3)*16 + hi*4;
                if (tct < 2) {
                    int d = tct*16 + lo;
#pragma unroll
                    for (int r = 0; r < 4; ++r)
                        *(bf16_t*)(smem + LDS_QS + (row0+r)*72 + d*2) = (bf16_t)((acc[ct][r] + qb) * scale);
                } else if (tct < 4) {
                    int d = (tct-2)*16 + lo;
#pragma unroll
                    for (int r = 0; r < 4; ++r)
                        *(bf16_t*)(smem + LDS_KS + (row0+r)*72 + d*2) = (bf16_t)(acc[ct][r] + qb);
                } else {
                    int d = (tct-4)*16 + lo;
#pragma unroll
                    for (int r = 0; r < 4; ++r)
                        *(bf16_t*)(smem + LDS_VST + d*144 + (row0+r)*2) = (bf16_t)(acc[ct][r] + qb);
                }
            }
        }
        __syncthreads();

        // ---- QK^T + bias + softmax (waves 0..3; wave = m-tile) ----
        if (w < 4) {
            const int m = w;
            bf16x8 aq = *(const bf16x8*)(smem + LDS_QS + (m*16 + lo)*72 + hi*16);
            f32x4 s[4];
#pragma unroll
            for (int ct = 0; ct < 4; ++ct) {
                bf16x8 bk = *(const bf16x8*)(smem + LDS_KS + (ct*16 + lo)*72 + hi*16);
                f32x4 zz = f32x4{0.f,0.f,0.f,0.f};
                s[ct] = __builtin_amdgcn_mfma_f32_16x16x32_bf16(aq, bk, zz, 0, 0, 0);
                float4 bv = biasL[((h*4 + m)*4 + ct)*64 + lane];
                s[ct][0] += bv.x; s[ct][1] += bv.y; s[ct][2] += bv.z; s[ct][3] += bv.w;
            }
            if (lo > 0) { s[3][0] = -1e30f; s[3][1] = -1e30f; s[3][2] = -1e30f; s[3][3] = -1e30f; } // cols 49..63
#pragma unroll
            for (int r = 0; r < 4; ++r) {
                float mx = fmaxf(fmaxf(s[0][r], s[1][r]), fmaxf(s[2][r], s[3][r]));
#pragma unroll
                for (int off = 1; off < 16; off <<= 1) mx = fmaxf(mx, __shfl_xor(mx, off));
                float sum = 0.f;
#pragma unroll
                for (int ct = 0; ct < 4; ++ct) { float e = __expf(s[ct][r] - mx); s[ct][r] = e; sum += e; }
#pragma unroll
                for (int off = 1; off < 16; off <<= 1) sum += __shfl_xor(sum, off);
                float rinv = 1.0f / sum;
                int row = m*16 + hi*4 + r;
                if (row < 49) {
#pragma unroll
                    for (int ct = 0; ct < 4; ++ct)
                        *(bf16_t*)(smem + LDS_P + row*144 + (ct*16 + lo)*2) = (bf16_t)(s[ct][r] * rinv);
                }
            }
        }
        __syncthreads();

        // ---- PV: all 8 waves, (mq, nq) ----
        {
            f32x4 o = f32x4{0.f,0.f,0.f,0.f};
#pragma unroll
            for (int ks = 0; ks < 2; ++ks) {
                bf16x8 ap = *(const bf16x8*)(smem + LDS_P   + (mq*16 + lo)*144 + ks*64 + hi*16);
                bf16x8 bv = *(const bf16x8*)(smem + LDS_VST + (nq*16 + lo)*144 + ks*64 + hi*16);
                o = __builtin_amdgcn_mfma_f32_16x16x32_bf16(ap, bv, o, 0, 0, 0);
            }
            int row0 = mq*16 + hi*4;
#pragma unroll
            for (int r = 0; r < 4; ++r)
                *(bf16_t*)(smem + LDS_OS + (row0+r)*72 + (nq*16 + lo)*2) = (bf16_t)o[r];
        }
        __syncthreads();

        // ---- proj partial accumulation: out += Os @ Pw_h ----
        {
            bf16x8 ao = *(const bf16x8*)(smem + LDS_OS + (mq*16 + lo)*72 + hi*16);
            const bf16_t* pwh = pwb + h*32;
#pragma unroll
            for (int ct = 0; ct < 12; ++ct) {
                int c2 = nq*192 + ct*16 + lo;
                bf16x8 b = *(const bf16x8*)(pwh + c2*384 + hi*8);
                accP[ct] = __builtin_amdgcn_mfma_f32_16x16x32_bf16(ao, b, accP[ct], 0, 0, 0);
            }
        }
        __syncthreads();  // protects Bsw/Qs/Ks/VsT/P/Os for next head
    }

    // ---- epilogue: add proj bias, store fp32 ----
    float* ow = out + (size_t)wi * (49*384);
#pragma unroll
    for (int ct = 0; ct < 12; ++ct) {
        int c2 = nq*192 + ct*16 + lo;
        float b = proj_b[c2];
#pragma unroll
        for (int r = 0; r < 4; ++r) {
            int row = mq*16 + hi*4 + r;
            if (row < 49) ow[row*384 + c2] = accP[ct][r] + b;
        }
    }
}

extern "C" void kernel_launch(void* const* d_in, const int* in_sizes, int n_in,
                              void* d_out, int out_size, void* d_ws, size_t ws_size,
                              hipStream_t stream)
{
    const float* x      = (const float*)d_in[0];
    const float* qkv_w  = (const float*)d_in[1];
    const float* qkv_b  = (const float*)d_in[2];
    const float* proj_w = (const float*)d_in[3];
    const float* proj_b = (const float*)d_in[4];
    const float* rpb    = (const float*)d_in[5];
    const int*   rel_idx= (const int*)d_in[6];
    char* ws = (char*)d_ws;

    const int total = 12*96*384 + 384*384 + 12*4*4*64*4 + 12*96;
    prep_kernel<<<(total + 255)/256, 256, 0, stream>>>(qkv_w, qkv_b, proj_w, rpb, rel_idx, ws);
    wattn_kernel<<<4096, 512, 0, stream>>>(x, proj_b, ws, (float*)d_out);
}

// Round 2
// 1935.500 us; speedup vs baseline: 1.0002x; 1.0002x over previous
//
#include <hip/hip_runtime.h>
#include <hip/hip_bf16.h>

typedef __bf16 bf16_t;
typedef __bf16 bf16x8 __attribute__((ext_vector_type(8)));
typedef float  f32x4  __attribute__((ext_vector_type(4)));

// ---------------- workspace layout (bytes) ----------------
#define WBT_OFF   0                                  // bf16 [12][96][384]  (qkv weights, transposed per head: [col][k])
#define PWB_OFF   (12*96*384*2)                      // bf16 [384][384]     (proj_w, row-major, same as source)
#define BIASL_OFF (PWB_OFF + 384*384*2)              // f32  [12][4][4][64][4]  (bias pre-gathered in C-frag layout)
#define QKVB_OFF  (BIASL_OFF + 12*4*4*64*4*4)        // f32  [12][96]       (qkv bias remapped)
// total ws needed = QKVB_OFF + 12*96*4 = 1,380,864 B

// ---------------- LDS layout (bytes) ----------------
#define LDS_XS   0        // bf16 [64][384], row stride 768 B, XOR-swizzled
#define LDS_BSW  49152    // bf16 [96][384], row stride 768 B, XOR-swizzled
#define LDS_QS   122880   // bf16 [64][36],  row stride 72 B
#define LDS_KS   127488   // bf16 [64][36],  row stride 72 B
#define LDS_VST  132096   // bf16 [32][72],  row stride 144 B  (V transposed: [d][j])
#define LDS_P    136704   // bf16 [64][72],  row stride 144 B  (softmax probs)
#define LDS_OS   145920   // bf16 [64][36],  row stride 72 B   (per-head attn out)
#define LDS_TOT  150528

__global__ void prep_kernel(const float* __restrict__ qkv_w,
                            const float* __restrict__ qkv_b,
                            const float* __restrict__ proj_w,
                            const float* __restrict__ rpb,
                            const int*   __restrict__ rel_idx,
                            char* __restrict__ ws)
{
    bf16_t* WbT   = (bf16_t*)(ws + WBT_OFF);
    bf16_t* pwb   = (bf16_t*)(ws + PWB_OFF);
    float*  biasL = (float*)(ws + BIASL_OFF);
    float*  qkvbL = (float*)(ws + QKVB_OFF);
    const int n_wbt  = 12*96*384;
    const int n_pwb  = 384*384;
    const int n_bias = 12*4*4*64*4;
    const int n_qb   = 12*96;
    int idx = blockIdx.x * blockDim.x + threadIdx.x;
    if (idx < n_wbt) {
        int h = idx / (96*384);
        int rem = idx % (96*384);
        int c = rem / 384, k = rem % 384;
        int s = c >> 5, cc = c & 31;           // s: 0=q,1=k,2=v
        WbT[idx] = (bf16_t)qkv_w[(s*384 + h*32 + cc)*384 + k];
    } else if (idx < n_wbt + n_pwb) {
        int i = idx - n_wbt;
        pwb[i] = (bf16_t)proj_w[i];
    } else if (idx < n_wbt + n_pwb + n_bias) {
        int li = idx - n_wbt - n_pwb;          // [h][m][ct][l][r]
        int r  = li & 3;
        int l  = (li >> 2) & 63;
        int ct = (li >> 8) & 3;
        int m  = (li >> 10) & 3;
        int h  = li >> 12;
        int i  = m*16 + ((l >> 4) << 2) + r;   // token row
        int j  = ct*16 + (l & 15);             // token col
        float v = 0.f;
        if (i < 49 && j < 49) v = rpb[rel_idx[i*49 + j]*12 + h];
        biasL[li] = v;
    } else if (idx < n_wbt + n_pwb + n_bias + n_qb) {
        int i = idx - n_wbt - n_pwb - n_bias;
        int h = i / 96, c = i % 96;
        int s = c >> 5, cc = c & 31;
        qkvbL[i] = qkv_b[s*384 + h*32 + cc];
    }
}

__launch_bounds__(512, 2)
__global__ void wattn_kernel(const float* __restrict__ x,
                             const float* __restrict__ proj_b,
                             const char*  __restrict__ ws,
                             float* __restrict__ out)
{
    __shared__ __attribute__((aligned(16))) char smem[LDS_TOT];

    const bf16_t* WbT   = (const bf16_t*)(ws + WBT_OFF);
    const bf16_t* pwb   = (const bf16_t*)(ws + PWB_OFF);
    const float4* biasL = (const float4*)(ws + BIASL_OFF);
    const float*  qkvbL = (const float*)(ws + QKVB_OFF);

    const int tid  = threadIdx.x;
    const int lane = tid & 63;
    const int w    = tid >> 6;      // wave 0..7
    const int lo   = lane & 15;
    const int hi   = lane >> 4;
    const int wi   = blockIdx.x;    // window index

    auto xs_addr = [&](int row, int kb) { return LDS_XS  + row*768 + (kb ^ ((row & 7) << 4)); };
    auto bs_addr = [&](int row, int kb) { return LDS_BSW + row*768 + (kb ^ ((row & 7) << 4)); };

    // ---- init: zero Xs pad rows (49..63) and all of P ----
    uint4 z4 = make_uint4(0u, 0u, 0u, 0u);
    for (int c = tid; c < 15*48; c += 512) {
        int row = 49 + c/48, kc = c%48;
        *(uint4*)(smem + xs_addr(row, kc*16)) = z4;
    }
    for (int c = tid; c < 9216/16; c += 512)
        *(uint4*)(smem + LDS_P + c*16) = z4;

    // ---- stage x (fp32 -> bf16, swizzled) ----
    const float* xw = x + (size_t)wi * (49*384);
    for (int c = tid; c < 49*48; c += 512) {
        int row = c/48, kc = c%48;
        float4 f0 = *(const float4*)(xw + row*384 + kc*8);
        float4 f1 = *(const float4*)(xw + row*384 + kc*8 + 4);
        bf16x8 t;
        t[0]=(bf16_t)f0.x; t[1]=(bf16_t)f0.y; t[2]=(bf16_t)f0.z; t[3]=(bf16_t)f0.w;
        t[4]=(bf16_t)f1.x; t[5]=(bf16_t)f1.y; t[6]=(bf16_t)f1.z; t[7]=(bf16_t)f1.w;
        *(bf16x8*)(smem + xs_addr(row, kc*16)) = t;
    }
    __syncthreads();

    const float scale = 0.17677669529663687f; // 1/sqrt(32)
    f32x4 accP[12];
#pragma unroll
    for (int i = 0; i < 12; ++i) accP[i] = f32x4{0.f, 0.f, 0.f, 0.f};

    const int mq = w >> 1;  // PV/proj m-tile
    const int nq = w & 1;   // PV n-tile / proj col-half

#pragma unroll 1
    for (int h = 0; h < 12; ++h) {
        // ---- stage per-head qkv weight slice [96][384] bf16 into LDS ----
        const bf16_t* wsrc = WbT + h*(96*384);
        for (int c = tid; c < 96*48; c += 512) {
            int row = c/48, kc = c%48;
            uint4 d = *(const uint4*)(wsrc + row*384 + kc*8);
            *(uint4*)(smem + bs_addr(row, kc*16)) = d;
        }
        __syncthreads();

        // ---- QKV GEMM: wave (m = w&3, nh2 = w>>2) computes cols nh2*48 + ct*16 ----
        {
            const int m = w & 3, nh2 = w >> 2;
            f32x4 acc[3];
#pragma unroll
            for (int i = 0; i < 3; ++i) acc[i] = f32x4{0.f,0.f,0.f,0.f};
#pragma unroll
            for (int kk = 0; kk < 12; ++kk) {
                bf16x8 a = *(const bf16x8*)(smem + xs_addr(m*16 + lo, kk*64 + hi*16));
#pragma unroll
                for (int ct = 0; ct < 3; ++ct) {
                    bf16x8 b = *(const bf16x8*)(smem + bs_addr(nh2*48 + ct*16 + lo, kk*64 + hi*16));
                    acc[ct] = __builtin_amdgcn_mfma_f32_16x16x32_bf16(a, b, acc[ct], 0, 0, 0);
                }
            }
            // bias add + scatter to Qs/Ks/VsT
#pragma unroll
            for (int ct = 0; ct < 3; ++ct) {
                int tct = nh2*3 + ct;                 // 0..5: 0,1=q  2,3=k  4,5=v
                float qb = qkvbL[h*96 + tct*16 + lo];
                int row0 = (w & 3)*16 + hi*4;
                if (tct < 2) {
                    int d = tct*16 + lo;
#pragma unroll
                    for (int r = 0; r < 4; ++r)
                        *(bf16_t*)(smem + LDS_QS + (row0+r)*72 + d*2) = (bf16_t)((acc[ct][r] + qb) * scale);
                } else if (tct < 4) {
                    int d = (tct-2)*16 + lo;
#pragma unroll
                    for (int r = 0; r < 4; ++r)
                        *(bf16_t*)(smem + LDS_KS + (row0+r)*72 + d*2) = (bf16_t)(acc[ct][r] + qb);
                } else {
                    int d = (tct-4)*16 + lo;
#pragma unroll
                    for (int r = 0; r < 4; ++r)
                        *(bf16_t*)(smem + LDS_VST + d*144 + (row0+r)*2) = (bf16_t)(acc[ct][r] + qb);
                }
            }
        }
        __syncthreads();

        // ---- QK^T + bias + softmax (waves 0..3; wave = m-tile) ----
        if (w < 4) {
            const int m = w;
            bf16x8 aq = *(const bf16x8*)(smem + LDS_QS + (m*16 + lo)*72 + hi*16);
            f32x4 s[4];
#pragma unroll
            for (int ct = 0; ct < 4; ++ct) {
                bf16x8 bk = *(const bf16x8*)(smem + LDS_KS + (ct*16 + lo)*72 + hi*16);
                f32x4 zz = f32x4{0.f,0.f,0.f,0.f};
                s[ct] = __builtin_amdgcn_mfma_f32_16x16x32_bf16(aq, bk, zz, 0, 0, 0);
                float4 bv = biasL[((h*4 + m)*4 + ct)*64 + lane];
                s[ct][0] += bv.x; s[ct][1] += bv.y; s[ct][2] += bv.z; s[ct][3] += bv.w;
            }
            if (lo > 0) { s[3][0] = -1e30f; s[3][1] = -1e30f; s[3][2] = -1e30f; s[3][3] = -1e30f; } // cols 49..63
#pragma unroll
            for (int r = 0; r < 4; ++r) {
                float mx = fmaxf(fmaxf(s[0][r], s[1][r]), fmaxf(s[2][r], s[3][r]));
#pragma unroll
                for (int off = 1; off < 16; off <<= 1) mx = fmaxf(mx, __shfl_xor(mx, off));
                float sum = 0.f;
#pragma unroll
                for (int ct = 0; ct < 4; ++ct) { float e = __expf(s[ct][r] - mx); s[ct][r] = e; sum += e; }
#pragma unroll
                for (int off = 1; off < 16; off <<= 1) sum += __shfl_xor(sum, off);
                float rinv = 1.0f / sum;
                int row = m*16 + hi*4 + r;
                if (row < 49) {
#pragma unroll
                    for (int ct = 0; ct < 4; ++ct)
                        *(bf16_t*)(smem + LDS_P + row*144 + (ct*16 + lo)*2) = (bf16_t)(s[ct][r] * rinv);
                }
            }
        }
        __syncthreads();

        // ---- PV: all 8 waves, (mq, nq) ----
        {
            f32x4 o = f32x4{0.f,0.f,0.f,0.f};
#pragma unroll
            for (int ks = 0; ks < 2; ++ks) {
                bf16x8 ap = *(const bf16x8*)(smem + LDS_P   + (mq*16 + lo)*144 + ks*64 + hi*16);
                bf16x8 bv = *(const bf16x8*)(smem + LDS_VST + (nq*16 + lo)*144 + ks*64 + hi*16);
                o = __builtin_amdgcn_mfma_f32_16x16x32_bf16(ap, bv, o, 0, 0, 0);
            }
            int row0 = mq*16 + hi*4;
#pragma unroll
            for (int r = 0; r < 4; ++r)
                *(bf16_t*)(smem + LDS_OS + (row0+r)*72 + (nq*16 + lo)*2) = (bf16_t)o[r];
        }
        __syncthreads();

        // ---- proj partial accumulation: out += Os @ Pw_h ----
        {
            bf16x8 ao = *(const bf16x8*)(smem + LDS_OS + (mq*16 + lo)*72 + hi*16);
            const bf16_t* pwh = pwb + h*32;
#pragma unroll
            for (int ct = 0; ct < 12; ++ct) {
                int c2 = nq*192 + ct*16 + lo;
                bf16x8 b = *(const bf16x8*)(pwh + c2*384 + hi*8);
                accP[ct] = __builtin_amdgcn_mfma_f32_16x16x32_bf16(ao, b, accP[ct], 0, 0, 0);
            }
        }
        __syncthreads();  // protects Bsw/Qs/Ks/VsT/P/Os for next head
    }

    // ---- epilogue: add proj bias, store fp32 ----
    float* ow = out + (size_t)wi * (49*384);
#pragma unroll
    for (int ct = 0; ct < 12; ++ct) {
        int c2 = nq*192 + ct*16 + lo;
        float b = proj_b[c2];
#pragma unroll
        for (int r = 0; r < 4; ++r) {
            int row = mq*16 + hi*4 + r;
            if (row < 49) ow[row*384 + c2] = accP[ct][r] + b;
        }
    }
}

extern "C" void kernel_launch(void* const* d_in, const int* in_sizes, int n_in,
                              void* d_out, int out_size, void* d_ws, size_t ws_size,
                              hipStream_t stream)
{
    const float* x      = (const float*)d_in[0];
    const float* qkv_w  = (const float*)d_in[1];
    const float* qkv_b  = (const float*)d_in[2];
    const float* proj_w = (const float*)d_in[3];
    const float* proj_b = (const float*)d_in[4];
    const float* rpb    = (const float*)d_in[5];
    const int*   rel_idx= (const int*)d_in[6];
    char* ws = (char*)d_ws;

    const int total = 12*96*384 + 384*384 + 12*4*4*64*4 + 12*96;
    prep_kernel<<<(total + 255)/256, 256, 0, stream>>>(qkv_w, qkv_b, proj_w, rpb, rel_idx, ws);
    wattn_kernel<<<4096, 512, 0, stream>>>(x, proj_b, ws, (float*)d_out);
}

// Round 3
// 1931.152 us; speedup vs baseline: 1.0024x; 1.0023x over previous
//
#include <hip/hip_runtime.h>
#include <hip/hip_bf16.h>

typedef __bf16 bf16_t;
typedef __bf16 bf16x8 __attribute__((ext_vector_type(8)));
typedef float  f32x4  __attribute__((ext_vector_type(4)));

// ---------------- workspace layout (bytes) ----------------
#define WBT_OFF   0                                  // bf16 [12][96][384]  (qkv weights, transposed per head: [col][k])
#define PWB_OFF   (12*96*384*2)                      // bf16 [384][384]     (proj_w, row-major, same as source)
#define BIASL_OFF (PWB_OFF + 384*384*2)              // f32  [12][4][4][64][4]  (bias pre-gathered in C-frag layout)
#define QKVB_OFF  (BIASL_OFF + 12*4*4*64*4*4)        // f32  [12][96]       (qkv bias remapped)
// total ws needed = QKVB_OFF + 12*96*4 = 1,380,864 B

// ---------------- LDS layout (bytes) ----------------
#define LDS_XS   0        // bf16 [64][384], row stride 768 B, XOR-swizzled
#define LDS_BSW  49152    // bf16 [96][384], row stride 768 B, XOR-swizzled
#define LDS_QS   122880   // bf16 [64][36],  row stride 72 B
#define LDS_KS   127488   // bf16 [64][36],  row stride 72 B
#define LDS_VST  132096   // bf16 [32][72],  row stride 144 B  (V transposed: [d][j])
#define LDS_P    136704   // bf16 [64][72],  row stride 144 B  (softmax probs)
#define LDS_OS   145920   // bf16 [64][36],  row stride 72 B   (per-head attn out)
#define LDS_TOT  150528

__global__ void prep_kernel(const float* __restrict__ qkv_w,
                            const float* __restrict__ qkv_b,
                            const float* __restrict__ proj_w,
                            const float* __restrict__ rpb,
                            const int*   __restrict__ rel_idx,
                            char* __restrict__ ws)
{
    bf16_t* WbT   = (bf16_t*)(ws + WBT_OFF);
    bf16_t* pwb   = (bf16_t*)(ws + PWB_OFF);
    float*  biasL = (float*)(ws + BIASL_OFF);
    float*  qkvbL = (float*)(ws + QKVB_OFF);
    const int n_wbt  = 12*96*384;
    const int n_pwb  = 384*384;
    const int n_bias = 12*4*4*64*4;
    const int n_qb   = 12*96;
    int idx = blockIdx.x * blockDim.x + threadIdx.x;
    if (idx < n_wbt) {
        int h = idx / (96*384);
        int rem = idx % (96*384);
        int c = rem / 384, k = rem % 384;
        int s = c >> 5, cc = c & 31;           // s: 0=q,1=k,2=v
        WbT[idx] = (bf16_t)qkv_w[(s*384 + h*32 + cc)*384 + k];
    } else if (idx < n_wbt + n_pwb) {
        int i = idx - n_wbt;
        pwb[i] = (bf16_t)proj_w[i];
    } else if (idx < n_wbt + n_pwb + n_bias) {
        int li = idx - n_wbt - n_pwb;          // [h][m][ct][l][r]
        int r  = li & 3;
        int l  = (li >> 2) & 63;
        int ct = (li >> 8) & 3;
        int m  = (li >> 10) & 3;
        int h  = li >> 12;
        int i  = m*16 + ((l >> 4) << 2) + r;   // token row
        int j  = ct*16 + (l & 15);             // token col
        float v = 0.f;
        if (i < 49 && j < 49) v = rpb[rel_idx[i*49 + j]*12 + h];
        biasL[li] = v;
    } else if (idx < n_wbt + n_pwb + n_bias + n_qb) {
        int i = idx - n_wbt - n_pwb - n_bias;
        int h = i / 96, c = i % 96;
        int s = c >> 5, cc = c & 31;
        qkvbL[i] = qkv_b[s*384 + h*32 + cc];
    }
}

__launch_bounds__(512, 2)
__global__ void wattn_kernel(const float* __restrict__ x,
                             const float* __restrict__ proj_b,
                             const char*  __restrict__ ws,
                             float* __restrict__ out)
{
    __shared__ __attribute__((aligned(16))) char smem[LDS_TOT];

    const bf16_t* WbT   = (const bf16_t*)(ws + WBT_OFF);
    const bf16_t* pwb   = (const bf16_t*)(ws + PWB_OFF);
    const float4* biasL = (const float4*)(ws + BIASL_OFF);
    const float*  qkvbL = (const float*)(ws + QKVB_OFF);

    const int tid  = threadIdx.x;
    const int lane = tid & 63;
    const int w    = tid >> 6;      // wave 0..7
    const int lo   = lane & 15;
    const int hi   = lane >> 4;
    const int wi   = blockIdx.x;    // window index

    auto xs_addr = [&](int row, int kb) { return LDS_XS  + row*768 + (kb ^ ((row & 7) << 4)); };
    auto bs_addr = [&](int row, int kb) { return LDS_BSW + row*768 + (kb ^ ((row & 7) << 4)); };

    // ---- init: zero Xs pad rows (49..63) and all of P ----
    uint4 z4 = make_uint4(0u, 0u, 0u, 0u);
    for (int c = tid; c < 15*48; c += 512) {
        int row = 49 + c/48, kc = c%48;
        *(uint4*)(smem + xs_addr(row, kc*16)) = z4;
    }
    for (int c = tid; c < 9216/16; c += 512)
        *(uint4*)(smem + LDS_P + c*16) = z4;

    // ---- stage x (fp32 -> bf16, swizzled) ----
    const float* xw = x + (size_t)wi * (49*384);
    for (int c = tid; c < 49*48; c += 512) {
        int row = c/48, kc = c%48;
        float4 f0 = *(const float4*)(xw + row*384 + kc*8);
        float4 f1 = *(const float4*)(xw + row*384 + kc*8 + 4);
        bf16x8 t;
        t[0]=(bf16_t)f0.x; t[1]=(bf16_t)f0.y; t[2]=(bf16_t)f0.z; t[3]=(bf16_t)f0.w;
        t[4]=(bf16_t)f1.x; t[5]=(bf16_t)f1.y; t[6]=(bf16_t)f1.z; t[7]=(bf16_t)f1.w;
        *(bf16x8*)(smem + xs_addr(row, kc*16)) = t;
    }
    __syncthreads();

    const float scale = 0.17677669529663687f; // 1/sqrt(32)
    f32x4 accP[12];
#pragma unroll
    for (int i = 0; i < 12; ++i) accP[i] = f32x4{0.f, 0.f, 0.f, 0.f};

    const int mq = w >> 1;  // PV/proj m-tile
    const int nq = w & 1;   // PV n-tile / proj col-half

#pragma unroll 1
    for (int h = 0; h < 12; ++h) {
        // ---- stage per-head qkv weight slice [96][384] bf16 into LDS ----
        const bf16_t* wsrc = WbT + h*(96*384);
        for (int c = tid; c < 96*48; c += 512) {
            int row = c/48, kc = c%48;
            uint4 d = *(const uint4*)(wsrc + row*384 + kc*8);
            *(uint4*)(smem + bs_addr(row, kc*16)) = d;
        }
        __syncthreads();

        // ---- QKV GEMM: wave (m = w&3, nh2 = w>>2) computes cols nh2*48 + ct*16 ----
        {
            const int m = w & 3, nh2 = w >> 2;
            f32x4 acc[3];
#pragma unroll
            for (int i = 0; i < 3; ++i) acc[i] = f32x4{0.f,0.f,0.f,0.f};
#pragma unroll
            for (int kk = 0; kk < 12; ++kk) {
                bf16x8 a = *(const bf16x8*)(smem + xs_addr(m*16 + lo, kk*64 + hi*16));
#pragma unroll
                for (int ct = 0; ct < 3; ++ct) {
                    bf16x8 b = *(const bf16x8*)(smem + bs_addr(nh2*48 + ct*16 + lo, kk*64 + hi*16));
                    acc[ct] = __builtin_amdgcn_mfma_f32_16x16x32_bf16(a, b, acc[ct], 0, 0, 0);
                }
            }
            // bias add + scatter to Qs/Ks/VsT
#pragma unroll
            for (int ct = 0; ct < 3; ++ct) {
                int tct = nh2*3 + ct;                 // 0..5: 0,1=q  2,3=k  4,5=v
                float qb = qkvbL[h*96 + tct*16 + lo];
                int row0 = (w & 3)*16 + hi*4;
                if (tct < 2) {
                    int d = tct*16 + lo;
#pragma unroll
                    for (int r = 0; r < 4; ++r)
                        *(bf16_t*)(smem + LDS_QS + (row0+r)*72 + d*2) = (bf16_t)((acc[ct][r] + qb) * scale);
                } else if (tct < 4) {
                    int d = (tct-2)*16 + lo;
#pragma unroll
                    for (int r = 0; r < 4; ++r)
                        *(bf16_t*)(smem + LDS_KS + (row0+r)*72 + d*2) = (bf16_t)(acc[ct][r] + qb);
                } else {
                    int d = (tct-4)*16 + lo;
#pragma unroll
                    for (int r = 0; r < 4; ++r)
                        *(bf16_t*)(smem + LDS_VST + d*144 + (row0+r)*2) = (bf16_t)(acc[ct][r] + qb);
                }
            }
        }
        __syncthreads();

        // ---- QK^T + bias + softmax (waves 0..3; wave = m-tile) ----
        if (w < 4) {
            const int m = w;
            bf16x8 aq = *(const bf16x8*)(smem + LDS_QS + (m*16 + lo)*72 + hi*16);
            f32x4 s[4];
#pragma unroll
            for (int ct = 0; ct < 4; ++ct) {
                bf16x8 bk = *(const bf16x8*)(smem + LDS_KS + (ct*16 + lo)*72 + hi*16);
                f32x4 zz = f32x4{0.f,0.f,0.f,0.f};
                s[ct] = __builtin_amdgcn_mfma_f32_16x16x32_bf16(aq, bk, zz, 0, 0, 0);
                float4 bv = biasL[((h*4 + m)*4 + ct)*64 + lane];
                s[ct][0] += bv.x; s[ct][1] += bv.y; s[ct][2] += bv.z; s[ct][3] += bv.w;
            }
            if (lo > 0) { s[3][0] = -1e30f; s[3][1] = -1e30f; s[3][2] = -1e30f; s[3][3] = -1e30f; } // cols 49..63
#pragma unroll
            for (int r = 0; r < 4; ++r) {
                float mx = fmaxf(fmaxf(s[0][r], s[1][r]), fmaxf(s[2][r], s[3][r]));
#pragma unroll
                for (int off = 1; off < 16; off <<= 1) mx = fmaxf(mx, __shfl_xor(mx, off));
                float sum = 0.f;
#pragma unroll
                for (int ct = 0; ct < 4; ++ct) { float e = __expf(s[ct][r] - mx); s[ct][r] = e; sum += e; }
#pragma unroll
                for (int off = 1; off < 16; off <<= 1) sum += __shfl_xor(sum, off);
                float rinv = 1.0f / sum;
                int row = m*16 + hi*4 + r;
                if (row < 49) {
#pragma unroll
                    for (int ct = 0; ct < 4; ++ct)
                        *(bf16_t*)(smem + LDS_P + row*144 + (ct*16 + lo)*2) = (bf16_t)(s[ct][r] * rinv);
                }
            }
        }
        __syncthreads();

        // ---- PV: all 8 waves, (mq, nq) ----
        {
            f32x4 o = f32x4{0.f,0.f,0.f,0.f};
#pragma unroll
            for (int ks = 0; ks < 2; ++ks) {
                bf16x8 ap = *(const bf16x8*)(smem + LDS_P   + (mq*16 + lo)*144 + ks*64 + hi*16);
                bf16x8 bv = *(const bf16x8*)(smem + LDS_VST + (nq*16 + lo)*144 + ks*64 + hi*16);
                o = __builtin_amdgcn_mfma_f32_16x16x32_bf16(ap, bv, o, 0, 0, 0);
            }
            int row0 = mq*16 + hi*4;
#pragma unroll
            for (int r = 0; r < 4; ++r)
                *(bf16_t*)(smem + LDS_OS + (row0+r)*72 + (nq*16 + lo)*2) = (bf16_t)o[r];
        }
        __syncthreads();

        // ---- proj partial accumulation: out += Os @ Pw_h ----
        {
            bf16x8 ao = *(const bf16x8*)(smem + LDS_OS + (mq*16 + lo)*72 + hi*16);
            const bf16_t* pwh = pwb + h*32;
#pragma unroll
            for (int ct = 0; ct < 12; ++ct) {
                int c2 = nq*192 + ct*16 + lo;
                bf16x8 b = *(const bf16x8*)(pwh + c2*384 + hi*8);
                accP[ct] = __builtin_amdgcn_mfma_f32_16x16x32_bf16(ao, b, accP[ct], 0, 0, 0);
            }
        }
        __syncthreads();  // protects Bsw/Qs/Ks/VsT/P/Os for next head
    }

    // ---- epilogue: add proj bias, store fp32 ----
    float* ow = out + (size_t)wi * (49*384);
#pragma unroll
    for (int ct = 0; ct < 12; ++ct) {
        int c2 = nq*192 + ct*16 + lo;
        float b = proj_b[c2];
#pragma unroll
        for (int r = 0; r < 4; ++r) {
            int row = mq*16 + hi*4 + r;
            if (row < 49) ow[row*384 + c2] = accP[ct][r] + b;
        }
    }
}

extern "C" void kernel_launch(void* const* d_in, const int* in_sizes, int n_in,
                              void* d_out, int out_size, void* d_ws, size_t ws_size,
                              hipStream_t stream)
{
    const float* x      = (const float*)d_in[0];
    const float* qkv_w  = (const float*)d_in[1];
    const float* qkv_b  = (const float*)d_in[2];
    const float* proj_w = (const float*)d_in[3];
    const float* proj_b = (const float*)d_in[4];
    const float* rpb    = (const float*)d_in[5];
    const int*   rel_idx= (const int*)d_in[6];
    char* ws = (char*)d_ws;

    const int total = 12*96*384 + 384*384 + 12*4*4*64*4 + 12*96;
    prep_kernel<<<(total + 255)/256, 256, 0, stream>>>(qkv_w, qkv_b, proj_w, rpb, rel_idx, ws);
    wattn_kernel<<<4096, 512, 0, stream>>>(x, proj_b, ws, (float*)d_out);
}

// Round 4
// 1450.449 us; speedup vs baseline: 1.3347x; 1.3314x over previous
//
#include <hip/hip_runtime.h>
#include <hip/hip_bf16.h>

typedef __bf16 bf16_t;
typedef __bf16 bf16x8 __attribute__((ext_vector_type(8)));
typedef __bf16 bf16x4 __attribute__((ext_vector_type(4)));
typedef float  f32x4  __attribute__((ext_vector_type(4)));

// ---------------- workspace layout (bytes) ----------------
#define WBT_OFF   0                                  // bf16 [12][96][384]  qkv weights, per-head [col][k]
#define PWB_OFF   (12*96*384*2)                      // bf16 [384][384]     proj_w row-major
#define BIASL_OFF (PWB_OFF + 384*384*2)              // f32  [12][4][4][64][4]  attn bias in C-frag layout (-1e30 for j>=49)
#define QKVB_OFF  (BIASL_OFF + 12*4*4*64*4*4)        // f32  [1152]         qkv bias remapped (head-major, unscaled)
#define QKV_OFF   1380864                            // bf16 [4096][12][3][64*32] padded Q(scaled)/K/V^T tiles
#define QKV_BYTES (4096ULL*12*3*2048*2)              // 603,979,776
#define O_OFF     (QKV_OFF + QKV_BYTES)              // 605,360,640
#define O_BYTES   (200704ULL*384*2)                  // bf16 [200704][384] attn output
#define WS_NEED   (O_OFF + O_BYTES)                  // 759,501,312

__global__ void prep_kernel(const float* __restrict__ qkv_w,
                            const float* __restrict__ qkv_b,
                            const float* __restrict__ proj_w,
                            const float* __restrict__ rpb,
                            const int*   __restrict__ rel_idx,
                            char* __restrict__ ws)
{
    bf16_t* WbT   = (bf16_t*)(ws + WBT_OFF);
    bf16_t* pwb   = (bf16_t*)(ws + PWB_OFF);
    float*  biasL = (float*)(ws + BIASL_OFF);
    float*  qkvbL = (float*)(ws + QKVB_OFF);
    const int n_wbt  = 12*96*384;
    const int n_pwb  = 384*384;
    const int n_bias = 12*4*4*64*4;
    const int n_qb   = 12*96;
    int idx = blockIdx.x * blockDim.x + threadIdx.x;
    if (idx < n_wbt) {
        int h = idx / (96*384);
        int rem = idx % (96*384);
        int c = rem / 384, k = rem % 384;
        int s = c >> 5, cc = c & 31;           // s: 0=q,1=k,2=v
        WbT[idx] = (bf16_t)qkv_w[(s*384 + h*32 + cc)*384 + k];
    } else if (idx < n_wbt + n_pwb) {
        int i = idx - n_wbt;
        pwb[i] = (bf16_t)proj_w[i];
    } else if (idx < n_wbt + n_pwb + n_bias) {
        int li = idx - n_wbt - n_pwb;          // [h][m][ct][l][r]
        int r  = li & 3;
        int l  = (li >> 2) & 63;
        int ct = (li >> 8) & 3;
        int m  = (li >> 10) & 3;
        int h  = li >> 12;
        int i  = m*16 + ((l >> 4) << 2) + r;   // token row
        int j  = ct*16 + (l & 15);             // token col
        float v;
        if (j >= 49)      v = -1e30f;          // mask padded key columns
        else if (i < 49)  v = rpb[rel_idx[i*49 + j]*12 + h];
        else              v = 0.f;
        biasL[li] = v;
    } else if (idx < n_wbt + n_pwb + n_bias + n_qb) {
        int i = idx - n_wbt - n_pwb - n_bias;
        int h = i / 96, c = i % 96;
        int s = c >> 5, cc = c & 31;
        qkvbL[i] = qkv_b[s*384 + h*32 + cc];
    }
}

// ==================== fast path: 3-kernel pipeline ====================

// K1: qkv projection GEMM. 1 block = 1 window x 1 col-third (4 heads).
__launch_bounds__(512, 4)
__global__ void qkv_gemm_kernel(const float* __restrict__ x,
                                char* __restrict__ ws)
{
    __shared__ __attribute__((aligned(16))) char smem[49152]; // bf16 [64][384] swizzled

    const int tid = threadIdx.x;
    const int lane = tid & 63, lo = lane & 15, hi = lane >> 4;
    const int w8 = tid >> 6, mw = w8 & 1, ng = w8 >> 1;
    const int bid = blockIdx.x;
    const int wi = bid / 3, third = bid % 3;

    auto xs_addr = [&](int row, int kb) { return row*768 + (kb ^ ((row & 7) << 4)); };

    uint4 z4 = make_uint4(0u,0u,0u,0u);
    for (int c = tid; c < 15*48; c += 512) {            // zero pad rows 49..63
        int row = 49 + c/48, kc = c%48;
        *(uint4*)(smem + xs_addr(row, kc*16)) = z4;
    }
    const float* xw = x + (size_t)wi * (49*384);
    for (int c = tid; c < 49*48; c += 512) {            // stage x fp32->bf16
        int row = c/48, kc = c%48;
        float4 f0 = *(const float4*)(xw + row*384 + kc*8);
        float4 f1 = *(const float4*)(xw + row*384 + kc*8 + 4);
        bf16x8 t;
        t[0]=(bf16_t)f0.x; t[1]=(bf16_t)f0.y; t[2]=(bf16_t)f0.z; t[3]=(bf16_t)f0.w;
        t[4]=(bf16_t)f1.x; t[5]=(bf16_t)f1.y; t[6]=(bf16_t)f1.z; t[7]=(bf16_t)f1.w;
        *(bf16x8*)(smem + xs_addr(row, kc*16)) = t;
    }
    __syncthreads();

    const int h = third*4 + ng;                         // head handled by this wave
    const bf16_t* WbT   = (const bf16_t*)(ws + WBT_OFF);
    const float*  biasQ = (const float*)(ws + QKVB_OFF);
    const bf16_t* bw = WbT + (size_t)(h*96 + lo)*384 + hi*8;

    f32x4 acc[2][6];
#pragma unroll
    for (int i = 0; i < 2; ++i)
#pragma unroll
        for (int j = 0; j < 6; ++j) acc[i][j] = f32x4{0.f,0.f,0.f,0.f};

#pragma unroll
    for (int kk = 0; kk < 12; ++kk) {
        bf16x8 a0 = *(const bf16x8*)(smem + xs_addr(mw*32 + lo,      kk*64 + hi*16));
        bf16x8 a1 = *(const bf16x8*)(smem + xs_addr(mw*32 + 16 + lo, kk*64 + hi*16));
#pragma unroll
        for (int nt = 0; nt < 6; ++nt) {
            bf16x8 b = *(const bf16x8*)(bw + nt*(16*384) + kk*32);
            acc[0][nt] = __builtin_amdgcn_mfma_f32_16x16x32_bf16(a0, b, acc[0][nt], 0,0,0);
            acc[1][nt] = __builtin_amdgcn_mfma_f32_16x16x32_bf16(a1, b, acc[1][nt], 0,0,0);
        }
    }

    const float scale = 0.17677669529663687f; // 1/sqrt(32)
    bf16_t* qkv = (bf16_t*)(ws + QKV_OFF) + ((size_t)(wi*12 + h))*3*2048;
#pragma unroll
    for (int nt = 0; nt < 6; ++nt) {
        const int s  = nt >> 1;          // 0=q,1=k,2=v
        const int db = (nt & 1) << 4;    // d-half base
        float bq = biasQ[h*96 + nt*16 + lo];
        bf16_t* base = qkv + s*2048;
#pragma unroll
        for (int mi = 0; mi < 2; ++mi) {
            int m = mw*2 + mi;
            if (s < 2) {                 // Q (scaled) / K row-major [64][32]
#pragma unroll
                for (int r = 0; r < 4; ++r) {
                    int row = m*16 + hi*4 + r;
                    float v = acc[mi][nt][r] + bq;
                    if (s == 0) v *= scale;
                    base[row*32 + db + lo] = (bf16_t)v;
                }
            } else {                     // V transposed [32][64]
                bf16x4 p;
#pragma unroll
                for (int r = 0; r < 4; ++r) p[r] = (bf16_t)(acc[mi][nt][r] + bq);
                *(bf16x4*)(base + (db + lo)*64 + m*16 + hi*4) = p;
            }
        }
    }
}

// K2: attention. 1 wave = 1 (window, head); no barriers.
__launch_bounds__(256)
__global__ void attn_kernel(char* __restrict__ ws)
{
    __shared__ __attribute__((aligned(16))) char smem[4*9216]; // P bf16 [64][72] per wave

    const int tid = threadIdx.x, lane = tid & 63, lo = lane & 15, hi = lane >> 4;
    const int wv = tid >> 6;
    const int w  = blockIdx.x;
    const int h  = blockIdx.y*4 + wv;
    char* P = smem + wv*9216;
    const char*   base = ws + QKV_OFF + (size_t)(w*12 + h)*12288;
    const float4* bL   = (const float4*)(ws + BIASL_OFF) + (size_t)h*16*64;

    bf16x8 aq[4], bk[4];
#pragma unroll
    for (int m = 0; m < 4; ++m)  aq[m]  = *(const bf16x8*)(base + (m*16+lo)*64 + hi*16);
#pragma unroll
    for (int ct = 0; ct < 4; ++ct) bk[ct] = *(const bf16x8*)(base + 4096 + (ct*16+lo)*64 + hi*16);

    const f32x4 zz = {0.f,0.f,0.f,0.f};
#pragma unroll
    for (int m = 0; m < 4; ++m) {
        f32x4 s[4];
#pragma unroll
        for (int ct = 0; ct < 4; ++ct) {
            s[ct] = __builtin_amdgcn_mfma_f32_16x16x32_bf16(aq[m], bk[ct], zz, 0,0,0);
            float4 bv = bL[(m*4 + ct)*64 + lane];
            s[ct][0]+=bv.x; s[ct][1]+=bv.y; s[ct][2]+=bv.z; s[ct][3]+=bv.w;
        }
#pragma unroll
        for (int r = 0; r < 4; ++r) {
            float mx = fmaxf(fmaxf(s[0][r],s[1][r]), fmaxf(s[2][r],s[3][r]));
#pragma unroll
            for (int off = 1; off < 16; off <<= 1) mx = fmaxf(mx, __shfl_xor(mx, off));
            float e0 = __expf(s[0][r]-mx), e1 = __expf(s[1][r]-mx);
            float e2 = __expf(s[2][r]-mx), e3 = __expf(s[3][r]-mx);
            float sum = e0+e1+e2+e3;
#pragma unroll
            for (int off = 1; off < 16; off <<= 1) sum += __shfl_xor(sum, off);
            float rinv = 1.0f / sum;
            int row = m*16 + hi*4 + r;
            *(bf16_t*)(P + row*144 + (0*16+lo)*2) = (bf16_t)(e0*rinv);
            *(bf16_t*)(P + row*144 + (1*16+lo)*2) = (bf16_t)(e1*rinv);
            *(bf16_t*)(P + row*144 + (2*16+lo)*2) = (bf16_t)(e2*rinv);
            *(bf16_t*)(P + row*144 + (3*16+lo)*2) = (bf16_t)(e3*rinv);
        }
    }
    asm volatile("s_waitcnt lgkmcnt(0)" ::: "memory");

    bf16_t* O = (bf16_t*)(ws + O_OFF);
#pragma unroll
    for (int m = 0; m < 4; ++m) {
#pragma unroll
        for (int dt = 0; dt < 2; ++dt) {
            f32x4 o = zz;
#pragma unroll
            for (int ks = 0; ks < 2; ++ks) {
                bf16x8 ap = *(const bf16x8*)(P + (m*16+lo)*144 + ks*64 + hi*16);
                bf16x8 bv = *(const bf16x8*)(base + 8192 + (dt*16+lo)*128 + ks*64 + hi*16);
                o = __builtin_amdgcn_mfma_f32_16x16x32_bf16(ap, bv, o, 0,0,0);
            }
#pragma unroll
            for (int r = 0; r < 4; ++r) {
                int row = m*16 + hi*4 + r;
                if (row < 49)
                    O[((size_t)w*49 + row)*384 + h*32 + dt*16 + lo] = (bf16_t)o[r];
            }
        }
    }
}

// K3: output projection GEMM. 1 block = 64 tokens, full 384 cols.
__launch_bounds__(512, 4)
__global__ void proj_gemm_kernel(const float* __restrict__ proj_b,
                                 const char* __restrict__ ws,
                                 float* __restrict__ out)
{
    __shared__ __attribute__((aligned(16))) char smem[49152];

    const int tid = threadIdx.x;
    const int lane = tid & 63, lo = lane & 15, hi = lane >> 4;
    const int w8 = tid >> 6, mw = w8 & 1, ng = w8 >> 1;
    const int mb = blockIdx.x;

    auto xs_addr = [&](int row, int kb) { return row*768 + (kb ^ ((row & 7) << 4)); };

    const bf16_t* O = (const bf16_t*)(ws + O_OFF) + (size_t)mb*64*384;
    for (int c = tid; c < 64*48; c += 512) {
        int row = c/48, kc = c%48;
        uint4 d = *(const uint4*)(O + row*384 + kc*8);
        *(uint4*)(smem + xs_addr(row, kc*16)) = d;
    }
    __syncthreads();

    const bf16_t* pw = (const bf16_t*)(ws + PWB_OFF);
    const bf16_t* bw = pw + (size_t)(ng*96 + lo)*384 + hi*8;

    f32x4 acc[2][6];
#pragma unroll
    for (int i = 0; i < 2; ++i)
#pragma unroll
        for (int j = 0; j < 6; ++j) acc[i][j] = f32x4{0.f,0.f,0.f,0.f};

#pragma unroll
    for (int kk = 0; kk < 12; ++kk) {
        bf16x8 a0 = *(const bf16x8*)(smem + xs_addr(mw*32 + lo,      kk*64 + hi*16));
        bf16x8 a1 = *(const bf16x8*)(smem + xs_addr(mw*32 + 16 + lo, kk*64 + hi*16));
#pragma unroll
        for (int nt = 0; nt < 6; ++nt) {
            bf16x8 b = *(const bf16x8*)(bw + nt*(16*384) + kk*32);
            acc[0][nt] = __builtin_amdgcn_mfma_f32_16x16x32_bf16(a0, b, acc[0][nt], 0,0,0);
            acc[1][nt] = __builtin_amdgcn_mfma_f32_16x16x32_bf16(a1, b, acc[1][nt], 0,0,0);
        }
    }

    float* ow = out + (size_t)mb*64*384;
#pragma unroll
    for (int nt = 0; nt < 6; ++nt) {
        int cc = ng*96 + nt*16 + lo;
        float pb = proj_b[cc];
#pragma unroll
        for (int mi = 0; mi < 2; ++mi) {
            int m = mw*2 + mi;
#pragma unroll
            for (int r = 0; r < 4; ++r)
                ow[(m*16 + hi*4 + r)*384 + cc] = acc[mi][nt][r] + pb;
        }
    }
}

// ==================== fallback: fused per-window kernel (round-3 passing) ====================

#define LDS_XS   0
#define LDS_BSW  49152
#define LDS_QS   122880
#define LDS_KS   127488
#define LDS_VST  132096
#define LDS_P    136704
#define LDS_OS   145920
#define LDS_TOT  150528

__launch_bounds__(512, 2)
__global__ void wattn_kernel(const float* __restrict__ x,
                             const float* __restrict__ proj_b,
                             const char*  __restrict__ ws,
                             float* __restrict__ out)
{
    __shared__ __attribute__((aligned(16))) char smem[LDS_TOT];

    const bf16_t* WbT   = (const bf16_t*)(ws + WBT_OFF);
    const bf16_t* pwb   = (const bf16_t*)(ws + PWB_OFF);
    const float4* biasL = (const float4*)(ws + BIASL_OFF);
    const float*  qkvbL = (const float*)(ws + QKVB_OFF);

    const int tid  = threadIdx.x;
    const int lane = tid & 63;
    const int w    = tid >> 6;
    const int lo   = lane & 15;
    const int hi   = lane >> 4;
    const int wi   = blockIdx.x;

    auto xs_addr = [&](int row, int kb) { return LDS_XS  + row*768 + (kb ^ ((row & 7) << 4)); };
    auto bs_addr = [&](int row, int kb) { return LDS_BSW + row*768 + (kb ^ ((row & 7) << 4)); };

    uint4 z4 = make_uint4(0u, 0u, 0u, 0u);
    for (int c = tid; c < 15*48; c += 512) {
        int row = 49 + c/48, kc = c%48;
        *(uint4*)(smem + xs_addr(row, kc*16)) = z4;
    }
    for (int c = tid; c < 9216/16; c += 512)
        *(uint4*)(smem + LDS_P + c*16) = z4;

    const float* xw = x + (size_t)wi * (49*384);
    for (int c = tid; c < 49*48; c += 512) {
        int row = c/48, kc = c%48;
        float4 f0 = *(const float4*)(xw + row*384 + kc*8);
        float4 f1 = *(const float4*)(xw + row*384 + kc*8 + 4);
        bf16x8 t;
        t[0]=(bf16_t)f0.x; t[1]=(bf16_t)f0.y; t[2]=(bf16_t)f0.z; t[3]=(bf16_t)f0.w;
        t[4]=(bf16_t)f1.x; t[5]=(bf16_t)f1.y; t[6]=(bf16_t)f1.z; t[7]=(bf16_t)f1.w;
        *(bf16x8*)(smem + xs_addr(row, kc*16)) = t;
    }
    __syncthreads();

    const float scale = 0.17677669529663687f;
    f32x4 accP[12];
#pragma unroll
    for (int i = 0; i < 12; ++i) accP[i] = f32x4{0.f, 0.f, 0.f, 0.f};

    const int mq = w >> 1;
    const int nq = w & 1;

#pragma unroll 1
    for (int h = 0; h < 12; ++h) {
        const bf16_t* wsrc = WbT + h*(96*384);
        for (int c = tid; c < 96*48; c += 512) {
            int row = c/48, kc = c%48;
            uint4 d = *(const uint4*)(wsrc + row*384 + kc*8);
            *(uint4*)(smem + bs_addr(row, kc*16)) = d;
        }
        __syncthreads();

        {
            const int m = w & 3, nh2 = w >> 2;
            f32x4 acc[3];
#pragma unroll
            for (int i = 0; i < 3; ++i) acc[i] = f32x4{0.f,0.f,0.f,0.f};
#pragma unroll
            for (int kk = 0; kk < 12; ++kk) {
                bf16x8 a = *(const bf16x8*)(smem + xs_addr(m*16 + lo, kk*64 + hi*16));
#pragma unroll
                for (int ct = 0; ct < 3; ++ct) {
                    bf16x8 b = *(const bf16x8*)(smem + bs_addr(nh2*48 + ct*16 + lo, kk*64 + hi*16));
                    acc[ct] = __builtin_amdgcn_mfma_f32_16x16x32_bf16(a, b, acc[ct], 0, 0, 0);
                }
            }
#pragma unroll
            for (int ct = 0; ct < 3; ++ct) {
                int tct = nh2*3 + ct;
                float qb = qkvbL[h*96 + tct*16 + lo];
                int row0 = (w & 3)*16 + hi*4;
                if (tct < 2) {
                    int d = tct*16 + lo;
#pragma unroll
                    for (int r = 0; r < 4; ++r)
                        *(bf16_t*)(smem + LDS_QS + (row0+r)*72 + d*2) = (bf16_t)((acc[ct][r] + qb) * scale);
                } else if (tct < 4) {
                    int d = (tct-2)*16 + lo;
#pragma unroll
                    for (int r = 0; r < 4; ++r)
                        *(bf16_t*)(smem + LDS_KS + (row0+r)*72 + d*2) = (bf16_t)(acc[ct][r] + qb);
                } else {
                    int d = (tct-4)*16 + lo;
#pragma unroll
                    for (int r = 0; r < 4; ++r)
                        *(bf16_t*)(smem + LDS_VST + d*144 + (row0+r)*2) = (bf16_t)(acc[ct][r] + qb);
                }
            }
        }
        __syncthreads();

        if (w < 4) {
            const int m = w;
            bf16x8 aq = *(const bf16x8*)(smem + LDS_QS + (m*16 + lo)*72 + hi*16);
            f32x4 s[4];
#pragma unroll
            for (int ct = 0; ct < 4; ++ct) {
                bf16x8 bk = *(const bf16x8*)(smem + LDS_KS + (ct*16 + lo)*72 + hi*16);
                f32x4 zz = f32x4{0.f,0.f,0.f,0.f};
                s[ct] = __builtin_amdgcn_mfma_f32_16x16x32_bf16(aq, bk, zz, 0, 0, 0);
                float4 bv = biasL[((h*4 + m)*4 + ct)*64 + lane];
                s[ct][0] += bv.x; s[ct][1] += bv.y; s[ct][2] += bv.z; s[ct][3] += bv.w;
            }
            if (lo > 0) { s[3][0] = -1e30f; s[3][1] = -1e30f; s[3][2] = -1e30f; s[3][3] = -1e30f; }
#pragma unroll
            for (int r = 0; r < 4; ++r) {
                float mx = fmaxf(fmaxf(s[0][r], s[1][r]), fmaxf(s[2][r], s[3][r]));
#pragma unroll
                for (int off = 1; off < 16; off <<= 1) mx = fmaxf(mx, __shfl_xor(mx, off));
                float sum = 0.f;
#pragma unroll
                for (int ct = 0; ct < 4; ++ct) { float e = __expf(s[ct][r] - mx); s[ct][r] = e; sum += e; }
#pragma unroll
                for (int off = 1; off < 16; off <<= 1) sum += __shfl_xor(sum, off);
                float rinv = 1.0f / sum;
                int row = m*16 + hi*4 + r;
                if (row < 49) {
#pragma unroll
                    for (int ct = 0; ct < 4; ++ct)
                        *(bf16_t*)(smem + LDS_P + row*144 + (ct*16 + lo)*2) = (bf16_t)(s[ct][r] * rinv);
                }
            }
        }
        __syncthreads();

        {
            f32x4 o = f32x4{0.f,0.f,0.f,0.f};
#pragma unroll
            for (int ks = 0; ks < 2; ++ks) {
                bf16x8 ap = *(const bf16x8*)(smem + LDS_P   + (mq*16 + lo)*144 + ks*64 + hi*16);
                bf16x8 bv = *(const bf16x8*)(smem + LDS_VST + (nq*16 + lo)*144 + ks*64 + hi*16);
                o = __builtin_amdgcn_mfma_f32_16x16x32_bf16(ap, bv, o, 0, 0, 0);
            }
            int row0 = mq*16 + hi*4;
#pragma unroll
            for (int r = 0; r < 4; ++r)
                *(bf16_t*)(smem + LDS_OS + (row0+r)*72 + (nq*16 + lo)*2) = (bf16_t)o[r];
        }
        __syncthreads();

        {
            bf16x8 ao = *(const bf16x8*)(smem + LDS_OS + (mq*16 + lo)*72 + hi*16);
            const bf16_t* pwh = pwb + h*32;
#pragma unroll
            for (int ct = 0; ct < 12; ++ct) {
                int c2 = nq*192 + ct*16 + lo;
                bf16x8 b = *(const bf16x8*)(pwh + c2*384 + hi*8);
                accP[ct] = __builtin_amdgcn_mfma_f32_16x16x32_bf16(ao, b, accP[ct], 0, 0, 0);
            }
        }
        __syncthreads();
    }

    float* ow = out + (size_t)wi * (49*384);
#pragma unroll
    for (int ct = 0; ct < 12; ++ct) {
        int c2 = nq*192 + ct*16 + lo;
        float b = proj_b[c2];
#pragma unroll
        for (int r = 0; r < 4; ++r) {
            int row = mq*16 + hi*4 + r;
            if (row < 49) ow[row*384 + c2] = accP[ct][r] + b;
        }
    }
}

extern "C" void kernel_launch(void* const* d_in, const int* in_sizes, int n_in,
                              void* d_out, int out_size, void* d_ws, size_t ws_size,
                              hipStream_t stream)
{
    const float* x      = (const float*)d_in[0];
    const float* qkv_w  = (const float*)d_in[1];
    const float* qkv_b  = (const float*)d_in[2];
    const float* proj_w = (const float*)d_in[3];
    const float* proj_b = (const float*)d_in[4];
    const float* rpb    = (const float*)d_in[5];
    const int*   rel_idx= (const int*)d_in[6];
    char* ws = (char*)d_ws;

    const int total = 12*96*384 + 384*384 + 12*4*4*64*4 + 12*96;
    prep_kernel<<<(total + 255)/256, 256, 0, stream>>>(qkv_w, qkv_b, proj_w, rpb, rel_idx, ws);

    if (ws_size >= (size_t)WS_NEED) {
        qkv_gemm_kernel<<<4096*3, 512, 0, stream>>>(x, ws);
        attn_kernel<<<dim3(4096, 3), 256, 0, stream>>>(ws);
        proj_gemm_kernel<<<3136, 512, 0, stream>>>(proj_b, ws, (float*)d_out);
    } else {
        wattn_kernel<<<4096, 512, 0, stream>>>(x, proj_b, ws, (float*)d_out);
    }
}